// Round 1
// baseline (2617.811 us; speedup 1.0000x reference)
//
#include <hip/hip_runtime.h>
#include <stdint.h>

// VerticalCompression: out[b,c,o,p] = (1/(rs[c,o]*rs[c,p])) *
//   sum_{i in nz(o)} sum_{w in nz(p)} comp[c,o,i] * A'[b,i,w] * comp[c,p,w]
// comp = mask*weight, A' = A with zeroed diagonal.
// Structure: mask rows have <=64 nnz (64 slots, possible duplicate collisions),
// columns <=8. Fused design: WG per (b,o): R[c][w] (bf16, LDS) then contract
// against all p rows. A read once from HBM, 7x more via L3 (A[b]=256MiB slice
// is L3-resident with o-major dispatch).

#define B_ 4
#define I_ 8192
#define O_ 1024
#define C_ 4
#define K_ 64

// ws layout (needs ~1.3 MiB):
//   idx : O_*K_ int32      @ 0        (256 KiB)  padded with 0
//   vals: O_*K_*C_ float   @ 262144   (1 MiB)    [o][j][c], padded with 0
//   rs  : O_*C_ float      @ 1310720  (16 KiB)   [o][c]
//   cnt : O_ int32         @ 1327104  (4 KiB)

__device__ __forceinline__ unsigned short f2bf(float f) {
    union { float f; unsigned u; } x; x.f = f;
    unsigned r = (x.u + 0x7FFFu + ((x.u >> 16) & 1u)) >> 16;  // RNE
    return (unsigned short)r;
}
__device__ __forceinline__ float bf2f(unsigned short s) {
    union { unsigned u; float f; } x; x.u = ((unsigned)s) << 16;
    return x.f;
}

// ---------------- CSR build: one block per output row o ----------------
__global__ __launch_bounds__(256) void build_csr(
    const float* __restrict__ mask, const float* __restrict__ weight,
    int* __restrict__ idx, float* __restrict__ vals,
    float* __restrict__ rs, int* __restrict__ cnt)
{
    __shared__ int s_cnt[256];
    __shared__ int s_off[256];
    __shared__ int s_idx[K_];
    __shared__ float s_v[K_ * C_];
    __shared__ int s_n;

    const int o = blockIdx.x;
    const int t = threadIdx.x;
    const float* mrow = mask + (size_t)o * I_;
    const int base = t * 32;

    int c = 0;
    for (int k = 0; k < 32; k += 4) {
        float4 m = *(const float4*)(mrow + base + k);
        c += (m.x != 0.f) + (m.y != 0.f) + (m.z != 0.f) + (m.w != 0.f);
    }
    s_cnt[t] = c;
    __syncthreads();
    if (t == 0) {
        int run = 0;
        for (int u = 0; u < 256; ++u) { s_off[u] = run; run += s_cnt[u]; }
        s_n = run;               // <= 64 by construction
        cnt[o] = run;
    }
    __syncthreads();
    int off = s_off[t];
    for (int k = 0; k < 32; ++k) {
        if (mrow[base + k] != 0.f) s_idx[off++] = base + k;   // ascending order
    }
    __syncthreads();
    const int n = s_n;
    if (t < K_) {
        const int j = t;
        int ii = 0;
        float4 v = make_float4(0.f, 0.f, 0.f, 0.f);
        if (j < n) {
            ii = s_idx[j];
            v.x = weight[((size_t)0 * O_ + o) * I_ + ii];
            v.y = weight[((size_t)1 * O_ + o) * I_ + ii];
            v.z = weight[((size_t)2 * O_ + o) * I_ + ii];
            v.w = weight[((size_t)3 * O_ + o) * I_ + ii];
        }
        idx[(size_t)o * K_ + j] = ii;
        *(float4*)(vals + ((size_t)o * K_ + j) * C_) = v;
        s_v[j * 4 + 0] = v.x; s_v[j * 4 + 1] = v.y;
        s_v[j * 4 + 2] = v.z; s_v[j * 4 + 3] = v.w;
    }
    __syncthreads();
    if (t < C_) {
        float s = 0.f;
        for (int j = 0; j < K_; ++j) s += s_v[j * 4 + t];
        rs[(size_t)o * C_ + t] = s;
    }
}

// ---------------- fused main kernel: one WG per (o, b) ----------------
__global__ __launch_bounds__(512, 4) void vc_fused(
    const float* __restrict__ A, const int* __restrict__ idx,
    const float* __restrict__ vals, const float* __restrict__ rs,
    const int* __restrict__ cnt, float* __restrict__ out)
{
    // R[w][c] packed bf16: 8192*4*2 = 64 KiB -> 2 blocks/CU
    __shared__ unsigned short R[I_ * C_];

    const int o = blockIdx.x;
    const int b = blockIdx.y;
    const int t = threadIdx.x;
    const float* Ab = A + (size_t)b * I_ * I_;
    const int* rowIdx = idx + (size_t)o * K_;                       // uniform
    const float4* rowVal = (const float4*)(vals + (size_t)o * K_ * C_); // uniform

    // ---- stage 1: R[c][w] = sum_j val[c][j] * A[b, i_j, w] ----
    for (int pass = 0; pass < 4; ++pass) {
        const int col4 = pass * 512 + t;        // float4 column index, 0..2047
        float4 c0 = make_float4(0.f, 0.f, 0.f, 0.f);
        float4 c1 = c0, c2 = c0, c3 = c0;       // acc per channel over 4 w's
        #pragma unroll 8
        for (int j = 0; j < K_; ++j) {
            const int ii = rowIdx[j];           // scalar
            const float4 v = rowVal[j];         // scalar (c0..c3 weights)
            const float4 a = ((const float4*)(Ab + (size_t)ii * I_))[col4];
            c0.x += v.x * a.x; c0.y += v.x * a.y; c0.z += v.x * a.z; c0.w += v.x * a.w;
            c1.x += v.y * a.x; c1.y += v.y * a.y; c1.z += v.y * a.z; c1.w += v.y * a.w;
            c2.x += v.z * a.x; c2.y += v.z * a.y; c2.z += v.z * a.z; c2.w += v.z * a.w;
            c3.x += v.w * a.x; c3.y += v.w * a.y; c3.z += v.w * a.z; c3.w += v.w * a.w;
        }
        const int w0 = col4 * 4;
        ushort4 p0; p0.x = f2bf(c0.x); p0.y = f2bf(c1.x); p0.z = f2bf(c2.x); p0.w = f2bf(c3.x);
        ushort4 p1; p1.x = f2bf(c0.y); p1.y = f2bf(c1.y); p1.z = f2bf(c2.y); p1.w = f2bf(c3.y);
        ushort4 p2; p2.x = f2bf(c0.z); p2.y = f2bf(c1.z); p2.z = f2bf(c2.z); p2.w = f2bf(c3.z);
        ushort4 p3; p3.x = f2bf(c0.w); p3.y = f2bf(c1.w); p3.z = f2bf(c2.w); p3.w = f2bf(c3.w);
        *(ushort4*)(R + (size_t)(w0 + 0) * 4) = p0;
        *(ushort4*)(R + (size_t)(w0 + 1) * 4) = p1;
        *(ushort4*)(R + (size_t)(w0 + 2) * 4) = p2;
        *(ushort4*)(R + (size_t)(w0 + 3) * 4) = p3;
    }
    __syncthreads();

    // ---- diagonal removal: R[c][i_j] -= val[c][j] * A[b,i_j,i_j] ----
    const int n = cnt[o];
    if (t < n) {                       // n<=64; real entries have distinct i
        const int ii = rowIdx[t];
        const float d = Ab[(size_t)ii * I_ + ii];
        const float4 v = rowVal[t];
        ushort4 r = *(ushort4*)(R + (size_t)ii * 4);
        r.x = f2bf(bf2f(r.x) - v.x * d);
        r.y = f2bf(bf2f(r.y) - v.y * d);
        r.z = f2bf(bf2f(r.z) - v.z * d);
        r.w = f2bf(bf2f(r.w) - v.w * d);
        *(ushort4*)(R + (size_t)ii * 4) = r;
    }
    __syncthreads();

    // ---- stage 2: out[b,c,o,p] = sum_{w in nz(p)} val_p[c] * R[c][w] ----
    const float4 rso = *(const float4*)(rs + (size_t)o * C_);   // uniform
    for (int p = t; p < O_; p += 512) {
        const int* pIdx = idx + (size_t)p * K_;
        const float4* pVal = (const float4*)(vals + (size_t)p * K_ * C_);
        float s0 = 0.f, s1 = 0.f, s2 = 0.f, s3 = 0.f;
        #pragma unroll 8
        for (int j = 0; j < K_; ++j) {
            const int w = pIdx[j];
            const float4 v = pVal[j];
            const ushort4 r = *(const ushort4*)(R + (size_t)w * 4);
            s0 += v.x * bf2f(r.x);
            s1 += v.y * bf2f(r.y);
            s2 += v.z * bf2f(r.z);
            s3 += v.w * bf2f(r.w);
        }
        const float4 rsp = *(const float4*)(rs + (size_t)p * C_);
        float n0 = rso.x * rsp.x; n0 = (n0 == 0.f) ? 1.f : n0;
        float n1 = rso.y * rsp.y; n1 = (n1 == 0.f) ? 1.f : n1;
        float n2 = rso.z * rsp.z; n2 = (n2 == 0.f) ? 1.f : n2;
        float n3 = rso.w * rsp.w; n3 = (n3 == 0.f) ? 1.f : n3;
        const size_t cstride = (size_t)O_ * O_;
        const size_t base = (((size_t)b * C_ + 0) * O_ + o) * O_ + p;
        out[base + 0 * cstride] = s0 / n0;
        out[base + 1 * cstride] = s1 / n1;
        out[base + 2 * cstride] = s2 / n2;
        out[base + 3 * cstride] = s3 / n3;
    }
}

extern "C" void kernel_launch(void* const* d_in, const int* in_sizes, int n_in,
                              void* d_out, int out_size, void* d_ws, size_t ws_size,
                              hipStream_t stream) {
    const float* A      = (const float*)d_in[0];   // (B, I, I) fp32
    const float* mask   = (const float*)d_in[1];   // (O, I)   fp32
    const float* weight = (const float*)d_in[2];   // (C, O, I) fp32
    float* out = (float*)d_out;                    // (B*C, O, O) fp32

    char* ws = (char*)d_ws;
    int*   idx  = (int*)(ws + 0);
    float* vals = (float*)(ws + 262144);
    float* rs   = (float*)(ws + 1310720);
    int*   cnt  = (int*)(ws + 1327104);

    build_csr<<<dim3(O_), dim3(256), 0, stream>>>(mask, weight, idx, vals, rs, cnt);
    vc_fused<<<dim3(O_, B_), dim3(512), 0, stream>>>(A, idx, vals, rs, cnt, out);
}